// Round 9
// baseline (678.489 us; speedup 1.0000x reference)
//
#include <hip/hip_runtime.h>
#include <math.h>

typedef float f32x4 __attribute__((ext_vector_type(4)));
typedef __attribute__((ext_vector_type(8))) short short8;

#define C_DIM  256
#define K_DIM  8192
#define HW     1024
#define N_ROWS 32768
#define N_OUT  8388608
#define TAU    0.75f

// ---------------- bf16 split helpers (RN-even) ----------------
__device__ __forceinline__ unsigned short f2bf(float v) {
    union { float f; unsigned u; } a; a.f = v;
    unsigned r = a.u + 0x7fffu + ((a.u >> 16) & 1u);
    return (unsigned short)(r >> 16);
}
__device__ __forceinline__ float bf2f(unsigned short b) {
    union { float f; unsigned u; } a; a.u = ((unsigned)b) << 16; return a.f;
}

// abuf (A_hi): [blk 128][ck 8][frag 16][lane 64][e 8] ushort = 16 MB
//   row = blk*256 + frag*16 + (lane&15); ch = ck*32 + (lane>>4)*8 + e
// ebuf (E hi+lo): [nt 128][ck 8][s 2][frag 4][lane 64][e 8] ushort = 8 MB
//   col = nt*64 + frag*16 + (lane&15); ch = ck*32 + (lane>>4)*8 + e

// ---------------- prepA: LDS-transposed, fully coalesced ----------------
__global__ void prepA_kernel(const float* __restrict__ x, unsigned short* __restrict__ abuf) {
    __shared__ float ldsT[256 * 65];
    const int tid = threadIdx.x;
    const int b = blockIdx.x >> 4, tq = blockIdx.x & 15;
    const int t0 = tq << 6;
    const int l = tid & 63, q = tid >> 6;
    const float* xb = x + ((size_t)b << 18) + t0;
    #pragma unroll 8
    for (int cg = 0; cg < 64; ++cg) {
        int c = (cg << 2) + q;
        ldsT[c * 65 + l] = xb[((size_t)c << 10) + l];     // 256B contiguous / wave
    }
    __syncthreads();
    const int slabblk = (b << 2) + (tq >> 2);
    const int fbase = (tq & 3) << 2;
    #pragma unroll
    for (int i = 0; i < 8; ++i) {
        int unit = (i << 2) + q;            // 0..31 = ck(8) x fsub(4)
        int ck = unit >> 2, fsub = unit & 3;
        int toff = (fsub << 4) + (l & 15);
        int ch0 = (ck << 5) + ((l >> 4) << 3);
        short8 hi;
        #pragma unroll
        for (int j = 0; j < 8; ++j) hi[j] = (short)f2bf(ldsT[(ch0 + j) * 65 + toff]);
        size_t base = (((size_t)slabblk * 8 + ck) * 16 + fbase + fsub) * 512 + l * 8;
        *(short8*)(abuf + base) = hi;       // 1KB contiguous / wave
    }
}

// ---------------- prepE: LDS-transposed; also e_norm and (optional) embedT ----------------
__global__ void prepE_kernel(const float* __restrict__ embed, unsigned short* __restrict__ ebuf,
                             float* __restrict__ e_norm, float* __restrict__ embedT) {
    __shared__ float ldsT[256 * 65];
    __shared__ float pnorm[256];
    const int tid = threadIdx.x;
    const int kq = blockIdx.x;              // 0..127
    const int col0 = kq << 6;
    const int l = tid & 63, q = tid >> 6;
    #pragma unroll 8
    for (int cg = 0; cg < 64; ++cg) {
        int c = (cg << 2) + q;
        ldsT[c * 65 + l] = embed[((size_t)c << 13) + col0 + l];
    }
    __syncthreads();
    {
        float s = 0.f;
        #pragma unroll 8
        for (int cc = 0; cc < 64; ++cc) {
            float v = ldsT[(q * 64 + cc) * 65 + l];
            s = __builtin_fmaf(v, v, s);
        }
        pnorm[q * 64 + l] = s;
    }
    __syncthreads();
    if (tid < 64)
        e_norm[col0 + tid] = (pnorm[tid] + pnorm[64 + tid]) + (pnorm[128 + tid] + pnorm[192 + tid]);
    #pragma unroll
    for (int i = 0; i < 16; ++i) {
        int unit = (i << 2) + q;            // 0..63 = ck(8) x s(2) x f(4)
        int f = unit & 3, s = (unit >> 2) & 1, ck = unit >> 3;
        int coff = (f << 4) + (l & 15);
        int ch0 = (ck << 5) + ((l >> 4) << 3);
        short8 w;
        #pragma unroll
        for (int j = 0; j < 8; ++j) {
            float v = ldsT[(ch0 + j) * 65 + coff];
            unsigned short h = f2bf(v);
            w[j] = (short)(s ? f2bf(v - bf2f(h)) : h);
        }
        size_t base = ((((size_t)kq * 8 + ck) * 2 + s) * 4 + f) * 512 + l * 8;
        *(short8*)(ebuf + base) = w;
    }
    if (embedT) {
        #pragma unroll 8
        for (int i = 0; i < 64; ++i)
            embedT[(size_t)(col0 + i) * 256 + tid] = ldsT[tid * 65 + i];
    }
}

#define GLDS(S, D) __builtin_amdgcn_global_load_lds(                              \
        (const __attribute__((address_space(1))) void*)(S),                       \
        (__attribute__((address_space(3))) void*)(D), 16, 0, 0)

// main: 256 blocks x 512 thr (8 waves = 4 wm x 2 wn). Block = 256 rows x 4096 cols.
// A_hi fully LDS-resident (128 KB, staged once). E loaded DIRECT to registers
// (ping-pong, 1-phase prefetch lead) -> NO barriers / waitcnts in the main loop.
// XCD swizzle: nh constant per XCD so each XCD's E half (4 MB) fits its L2.
__launch_bounds__(512, 2)
__global__ void vq_main(const unsigned short* __restrict__ abuf,
                        const unsigned short* __restrict__ ebuf,
                        const float* __restrict__ e_norm,
                        float4* __restrict__ res) {
    __shared__ unsigned short ldsA[65536];      // 128 KB: all 8 ck chunks
    const int tid  = threadIdx.x;
    const int lane = tid & 63;
    const int wid  = tid >> 6;
    const int wm   = wid >> 1, wn = wid & 1;
    const int bid  = blockIdx.x;
    const int xcd  = bid & 7;                   // round-robin dispatch -> XCD id
    const int nh   = xcd >> 2;                  // same nh for all blocks on an XCD
    const int mtB  = ((bid >> 3) << 2) + (xcd & 3);
    const unsigned short* aSlab = abuf + (size_t)mtB * 65536u;

    // one-time A stage: whole 128 KB slab, linear
    #pragma unroll
    for (int i = 0; i < 16; ++i)
        GLDS(aSlab + i * 4096 + tid * 8, ldsA + i * 4096 + tid * 8);

    const size_t ntBase = (size_t)(nh * 64 + wn * 32);

    float d1[16], d2[16]; int i1[16], i2[16];
    #pragma unroll
    for (int s = 0; s < 16; ++s) { d1[s] = INFINITY; d2[s] = INFINITY; i1[s] = 0; i2[s] = 0; }

    // E phase-0 into ping regs (direct global -> VGPR, coalesced 1KB/load)
    short8 eha[4], ela[4], ehb[4], elb[4];
    {
        const unsigned short* src = ebuf + ntBase * 32768u + lane * 8;
        #pragma unroll
        for (int cf = 0; cf < 4; ++cf) {
            eha[cf] = *(const short8*)(src + cf * 512);
            ela[cf] = *(const short8*)(src + 2048 + cf * 512);
        }
    }

    asm volatile("s_waitcnt vmcnt(0)" ::: "memory");
    __syncthreads();        // ldsA visible; last sync in the kernel

    #pragma unroll 1
    for (int ntl = 0; ntl < 32; ++ntl) {
        const int colb = nh * 4096 + wn * 2048 + ntl * 64 + (lane & 15);
        float e2v[4];
        #pragma unroll
        for (int cf = 0; cf < 4; ++cf) e2v[cf] = e_norm[colb + cf * 16];

        f32x4 acc[4][4];
        #pragma unroll
        for (int mi = 0; mi < 4; ++mi)
            #pragma unroll
            for (int cf = 0; cf < 4; ++cf) acc[mi][cf] = (f32x4){0.f, 0.f, 0.f, 0.f};

        #pragma unroll
        for (int kks = 0; kks < 4; ++kks) {
            // ---- even phase p = ntl*8 + 2*kks: consume a-regs (eha/ela), prefetch p+1 -> b
            {
                const int np = ntl * 8 + 2 * kks + 1;       // always < 256
                const unsigned short* nsrc =
                    ebuf + (ntBase + (np >> 3)) * 32768u + (np & 7) * 4096 + lane * 8;
                #pragma unroll
                for (int cf = 0; cf < 4; ++cf) {
                    ehb[cf] = *(const short8*)(nsrc + cf * 512);
                    elb[cf] = *(const short8*)(nsrc + 2048 + cf * 512);
                }
                short8 ah[4];
                #pragma unroll
                for (int mi = 0; mi < 4; ++mi)
                    ah[mi] = *(const short8*)(ldsA + (2 * kks) * 8192 + (wm * 4 + mi) * 512 + lane * 8);
                __builtin_amdgcn_s_setprio(1);
                #pragma unroll
                for (int cf = 0; cf < 4; ++cf)
                    #pragma unroll
                    for (int mi = 0; mi < 4; ++mi) {
                        acc[mi][cf] = __builtin_amdgcn_mfma_f32_16x16x32_bf16(ah[mi], eha[cf], acc[mi][cf], 0, 0, 0);
                        acc[mi][cf] = __builtin_amdgcn_mfma_f32_16x16x32_bf16(ah[mi], ela[cf], acc[mi][cf], 0, 0, 0);
                    }
                __builtin_amdgcn_s_setprio(0);
            }
            // ---- odd phase p+1: consume b, prefetch p+2 -> a (guard end)
            {
                const int np = ntl * 8 + 2 * kks + 2;
                if (np < 256) {
                    const unsigned short* nsrc =
                        ebuf + (ntBase + (np >> 3)) * 32768u + (np & 7) * 4096 + lane * 8;
                    #pragma unroll
                    for (int cf = 0; cf < 4; ++cf) {
                        eha[cf] = *(const short8*)(nsrc + cf * 512);
                        ela[cf] = *(const short8*)(nsrc + 2048 + cf * 512);
                    }
                }
                short8 ah[4];
                #pragma unroll
                for (int mi = 0; mi < 4; ++mi)
                    ah[mi] = *(const short8*)(ldsA + (2 * kks + 1) * 8192 + (wm * 4 + mi) * 512 + lane * 8);
                __builtin_amdgcn_s_setprio(1);
                #pragma unroll
                for (int cf = 0; cf < 4; ++cf)
                    #pragma unroll
                    for (int mi = 0; mi < 4; ++mi) {
                        acc[mi][cf] = __builtin_amdgcn_mfma_f32_16x16x32_bf16(ah[mi], ehb[cf], acc[mi][cf], 0, 0, 0);
                        acc[mi][cf] = __builtin_amdgcn_mfma_f32_16x16x32_bf16(ah[mi], elb[cf], acc[mi][cf], 0, 0, 0);
                    }
                __builtin_amdgcn_s_setprio(0);
            }
        }

        // top-2 update (cmp scale: e2 - 2*dot; z2 row-constant cancels)
        #pragma unroll
        for (int cf = 0; cf < 4; ++cf) {
            const int idx = colb + cf * 16;
            #pragma unroll
            for (int mi = 0; mi < 4; ++mi)
                #pragma unroll
                for (int r = 0; r < 4; ++r) {
                    const int s = mi * 4 + r;
                    float d = __builtin_fmaf(-2.f, acc[mi][cf][r], e2v[cf]);
                    bool b1 = d < d1[s];
                    bool b2 = d < d2[s];
                    d2[s] = b1 ? d1[s] : (b2 ? d : d2[s]);
                    i2[s] = b1 ? i1[s] : (b2 ? idx : i2[s]);
                    d1[s] = b1 ? d : d1[s];
                    i1[s] = b1 ? idx : i1[s];
                }
        }
    }

    // reduce top-2 across lane bits 0..2 -> 2 lists per (row, wave), lst = lane bit 3
    #pragma unroll
    for (int s = 0; s < 16; ++s) {
        float a1 = d1[s], a2 = d2[s]; int x1 = i1[s], x2 = i2[s];
        #pragma unroll
        for (int m = 1; m < 8; m <<= 1) {
            float o1 = __shfl_xor(a1, m, 64), o2 = __shfl_xor(a2, m, 64);
            int  oi1 = __shfl_xor(x1, m, 64), oi2 = __shfl_xor(x2, m, 64);
            bool ow = (o1 < a1) || (o1 == a1 && oi1 < x1);
            float w1v = ow ? o1 : a1; int w1i = ow ? oi1 : x1;
            float l1  = ow ? a1 : o1; int l1i = ow ? x1 : oi1;
            float c2  = ow ? o2 : a2; int c2i = ow ? oi2 : x2;
            bool sw = (c2 < l1) || (c2 == l1 && c2i < l1i);
            a1 = w1v; x1 = w1i;
            a2 = sw ? c2 : l1; x2 = sw ? c2i : l1i;
        }
        d1[s] = a1; d2[s] = a2; i1[s] = x1; i2[s] = x2;
    }
    // 8 col-disjoint lists per row: slot = nh*4 + wn*2 + lst  (unique writer)
    if ((lane & 7) == 0) {
        const int lst = (lane >> 3) & 1;
        const int h = lane >> 4;
        const int slot = nh * 4 + wn * 2 + lst;
        const int rowbase = (mtB << 8) + wm * 64 + (h << 2);
        #pragma unroll
        for (int mi = 0; mi < 4; ++mi)
            #pragma unroll
            for (int r = 0; r < 4; ++r) {
                const int s = mi * 4 + r;
                int row = rowbase + mi * 16 + r;
                float4 v; v.x = d1[s]; v.y = d2[s];
                v.z = __int_as_float(i1[s]); v.w = __int_as_float(i2[s]);
                res[row * 8 + slot] = v;
            }
    }
}

// merge 8 lists (16 cands, col-disjoint) + exact fp32 recheck of near-ties
__global__ void merge_kernel(const float* __restrict__ x, const float* __restrict__ embed,
                             const float* __restrict__ e_norm,
                             const float4* __restrict__ res, int* __restrict__ ids_final) {
    int row = blockIdx.x * 256 + threadIdx.x;
    float4 v[8];
    #pragma unroll
    for (int j = 0; j < 8; ++j) v[j] = res[row * 8 + j];
    float w1 = INFINITY; int wi = 0x7fffffff;
    #pragma unroll
    for (int j = 0; j < 8; ++j) {
        float d = v[j].x; int i = __float_as_int(v[j].z);
        if (d < w1 || (d == w1 && i < wi)) { w1 = d; wi = i; }
    }
    float w2 = INFINITY;
    #pragma unroll
    for (int j = 0; j < 8; ++j) {
        if (__float_as_int(v[j].z) != wi && v[j].x < w2) w2 = v[j].x;
        if (__float_as_int(v[j].w) != wi && v[j].y < w2) w2 = v[j].y;
    }
    int id = wi;
    if (w2 - w1 <= TAU) {
        int b = row >> 10, t = row & 1023;
        const float* xb = x + ((size_t)b << 18) + t;
        float bd = INFINITY; int bi = 0x7fffffff;
        float thr = w1 + TAU;
        #pragma unroll
        for (int j = 0; j < 8; ++j)
            #pragma unroll
            for (int sl = 0; sl < 2; ++sl) {
                float dap = sl ? v[j].y : v[j].x;
                int k = __float_as_int(sl ? v[j].w : v[j].z);
                if (dap <= thr) {
                    float dot = 0.f;
                    for (int c = 0; c < C_DIM; ++c)
                        dot = __builtin_fmaf(xb[(size_t)c << 10], embed[((size_t)c << 13) + k], dot);
                    float dd = __fadd_rn(e_norm[k], -__fmul_rn(2.0f, dot));
                    if (dd < bd || (dd == bd && k < bi)) { bd = dd; bi = k; }
                }
            }
        id = bi;
    }
    ids_final[row] = id;
}

// out via embedT: contiguous 1KB row gathers staged through padded LDS
__global__ void outT_kernel(const float* __restrict__ embedT, const int* __restrict__ ids_final,
                            float* __restrict__ out, float* __restrict__ ids_out) {
    __shared__ float fo[64 * 257];
    __shared__ int idsl[64];
    const int blk = blockIdx.x;         // 512 = b(32) x tchunk(16)
    const int b = blk >> 4, t0 = (blk & 15) << 6;
    const int tid = threadIdx.x;
    const int l = tid & 63, q = tid >> 6;
    if (tid < 64) {
        int t = t0 + tid;
        int id = ids_final[(b << 10) + t];
        idsl[tid] = id;
        int n = (b << 10) + ((t & 31) << 5) + (t >> 5);
        ids_out[n] = (float)id;
    }
    __syncthreads();
    #pragma unroll
    for (int i = 0; i < 16; ++i) {
        int slot = (i << 2) + q;
        const float* src = embedT + (size_t)idsl[slot] * 256;
        #pragma unroll
        for (int seg = 0; seg < 4; ++seg)
            fo[slot * 257 + (seg << 6) + l] = src[(seg << 6) + l];
    }
    __syncthreads();
    float* ob = out + ((size_t)b << 18) + t0;
    #pragma unroll 8
    for (int ci = 0; ci < 64; ++ci) {
        int c = (ci << 2) + q;
        ob[((size_t)c << 10) + l] = fo[l * 257 + c];
    }
}

// fallback out: column gather from embed
__global__ void out_kernel(const float* __restrict__ embed, const int* __restrict__ ids_final,
                           float* __restrict__ out, float* __restrict__ ids_out) {
    const int blk = blockIdx.x;
    const int b = blk >> 4, t0 = (blk & 15) << 6;
    const int tid = threadIdx.x;
    const int t_off = tid & 63, w4 = tid >> 6;
    if (tid < 64) {
        int t = t0 + tid;
        int id = ids_final[(b << 10) + t];
        int n = (b << 10) + ((t & 31) << 5) + (t >> 5);
        ids_out[n] = (float)id;
    }
    const int myid = ids_final[(b << 10) + t0 + t_off];
    const float* ecol = embed + myid;
    float* ob = out + b * (C_DIM * HW) + t0 + t_off;
    #pragma unroll 4
    for (int c = w4; c < C_DIM; c += 4)
        ob[c * HW] = ecol[c * K_DIM];
}

extern "C" void kernel_launch(void* const* d_in, const int* in_sizes, int n_in,
                              void* d_out, int out_size, void* d_ws, size_t ws_size,
                              hipStream_t stream) {
    const float* x     = (const float*)d_in[0];
    const float* embed = (const float*)d_in[1];
    float* out = (float*)d_out;
    float* ids_out = out + N_OUT;

    // d_out scratch (sequential lifetimes, disjoint): abuf 16MB @0, res 4MB @16MB
    unsigned short* abuf = (unsigned short*)d_out;
    float4* res = (float4*)((char*)d_out + (16u << 20));

    // ws: ebuf 8MB | e_norm 32KB | ids_final 128KB | embedT 8MB (optional)
    unsigned short* ebuf = (unsigned short*)d_ws;
    float* e_norm    = (float*)((char*)d_ws + 8388608u);
    int*   ids_final = (int*)((char*)d_ws + 8388608u + 32768u);
    size_t embT_off  = 8388608u + 32768u + 131072u;
    bool useT = (ws_size >= embT_off + 8388608u);
    float* embedT = useT ? (float*)((char*)d_ws + embT_off) : nullptr;

    prepA_kernel<<<512, 256, 0, stream>>>(x, abuf);
    prepE_kernel<<<128, 256, 0, stream>>>(embed, ebuf, e_norm, embedT);
    vq_main<<<256, 512, 0, stream>>>(abuf, ebuf, e_norm, res);
    merge_kernel<<<N_ROWS / 256, 256, 0, stream>>>(x, embed, e_norm, res, ids_final);
    if (useT) outT_kernel<<<512, 256, 0, stream>>>(embedT, ids_final, out, ids_out);
    else      out_kernel<<<512, 256, 0, stream>>>(embed, ids_final, out, ids_out);
}